// Round 8
// baseline (307.025 us; speedup 1.0000x reference)
//
#include <hip/hip_runtime.h>

#define NTOK 32768      // 8*4096 tokens
#define HDIM 1024
#define NEXP 64
#define TK   8
#define NB   8
#define SEQ  4096

// ---- GEMM kernel geometry (identical to R7) ----
#define MB    128               // tokens per block
#define KC    32                // K per chunk (one K32 MFMA step)
#define NCH   (HDIM / KC)       // 32 chunks
#define NTHR  512               // 8 waves: wm=w>>1 (4x32 rows), wn=w&1 (2x32 experts)
#define NBLK  (NTOK / MB)       // 256 blocks

typedef __attribute__((ext_vector_type(8))) short bf16x8;   // 8 bf16 = 4 VGPRs
typedef __attribute__((ext_vector_type(4))) float f32x4;

union BF8 { bf16x8 v; unsigned u[4]; };

__device__ inline unsigned f2bf(float x) {          // RTN-even fp32 -> bf16 bits
    unsigned u = __float_as_uint(x);
    return (u + 0x7FFFu + ((u >> 16) & 1u)) >> 16;
}

__device__ inline void split4(float4 v, unsigned* hp, unsigned* lp) {
    unsigned h0 = f2bf(v.x), h1 = f2bf(v.y), h2 = f2bf(v.z), h3 = f2bf(v.w);
    unsigned l0 = f2bf(v.x - __uint_as_float(h0 << 16));
    unsigned l1 = f2bf(v.y - __uint_as_float(h1 << 16));
    unsigned l2 = f2bf(v.z - __uint_as_float(h2 << 16));
    unsigned l3 = f2bf(v.w - __uint_as_float(h3 << 16));
    hp[0] = h0 | (h1 << 16); hp[1] = h2 | (h3 << 16);
    lp[0] = l0 | (l1 << 16); lp[1] = l2 | (l3 << 16);
}

// One-time: split W into Dekker hi/lo bf16 in MFMA B-fragment order:
// slot = kk*4 + n (kk = K32-chunk 0..31, n = expert-16-group 0..3), 64 lanes
// x 16B per slot; lane l -> B[e=n*16+(l&15)][k=kk*32+(l>>4)*8 .. +8].
__global__ void wsplit(const float* __restrict__ w,
                       unsigned short* __restrict__ whi,
                       unsigned short* __restrict__ wlo)
{
    int T = blockIdx.x * 256 + threadIdx.x;     // 8192 threads = 128 slots x 64
    int slot = T >> 6, l = T & 63;
    int c = slot >> 3, s = (slot >> 2) & 1, n = slot & 3;
    int e = n * 16 + (l & 15);
    int k = c * 64 + s * 32 + (l >> 4) * 8;     // == (slot>>2)*32 + (l>>4)*8
    const float* src = w + (size_t)e * HDIM + k;
    float4 v0 = *(const float4*)(src);
    float4 v1 = *(const float4*)(src + 4);
    unsigned hp[4], lp[4];
    split4(v0, &hp[0], &lp[0]);
    split4(v1, &hp[2], &lp[2]);
    ((uint4*)whi)[T] = make_uint4(hp[0], hp[1], hp[2], hp[3]);
    ((uint4*)wlo)[T] = make_uint4(lp[0], lp[1], lp[2], lp[3]);
}

// R8 ABLATION KERNEL: perfectly-sequential copy of the input buffer to the
// workspace. Purpose: isolate {buffer identity} x {access pattern}. Every
// GEMM variant R0-R7 read `hidden` as 16 rows x 128B at 4KB stride and pinned
// at ~1.7 TB/s effective; the only fast memory ops observed are harness
// WRITES to workspace (6.9 TB/s). This kernel's rocprof row measures
// sequential READ bandwidth on the input buffer; moe_gemm below (byte-identical
// to R7) now reads the copy -> same pattern, different buffer.
__global__ __launch_bounds__(256) void hcopy(const float4* __restrict__ src,
                                             float4* __restrict__ dst)
{
    const size_t n = (size_t)NTOK * HDIM / 4;               // 8.4M float4
    const size_t stride = (size_t)gridDim.x * blockDim.x;
    for (size_t i = (size_t)blockIdx.x * blockDim.x + threadIdx.x;
         i < n; i += stride)
        dst[i] = src[i];
}

// Identical to R7 (no LDS, no barriers, 2-set register pipeline) except the
// A operand comes from the workspace copy.
__global__ __launch_bounds__(NTHR, 4) void moe_gemm(
    const float* __restrict__ hsrc,             // [NTOK][HDIM] fp32 (copy)
    const unsigned short* __restrict__ w2hi,    // frag-ordered bf16 hi
    const unsigned short* __restrict__ w2lo,    // frag-ordered bf16 lo
    float* __restrict__ logits)                 // [NTOK][NEXP] fp32
{
    const int tid = threadIdx.x;
    const int w   = tid >> 6;           // 0..7
    const int l   = tid & 63;
    const int m   = l & 15;
    const int q   = l >> 4;
    const int wm  = w >> 1;             // token group: rows [32*wm, 32*wm+32)
    const int wn  = w & 1;              // expert group: cols [32*wn, 32*wn+32)
    const size_t t0 = (size_t)blockIdx.x * MB;

    const float* aR0 = hsrc + (t0 + wm * 32 + m) * HDIM + q * 8;
    const float* aR1 = aR0 + 16 * HDIM;
    const unsigned short* bBase = w2hi;
    const unsigned short* lBase = w2lo;
    const int bLane = (wn * 2) * 512 + l * 8;

    struct Regs {
        float4 a00, a01, a10, a11;      // A m-tile 0/1, k-half 0/1
        bf16x8 bh0, bh1, bl0, bl1;      // B hi/lo, n=0/1
    };

    f32x4 acc[2][2];
#pragma unroll
    for (int mt = 0; mt < 2; ++mt)
#pragma unroll
        for (int n = 0; n < 2; ++n) acc[mt][n] = (f32x4)0.f;

    auto loadc = [&](int kk, Regs& R) {
        R.a00 = *(const float4*)(aR0 + kk * KC);
        R.a01 = *(const float4*)(aR0 + kk * KC + 4);
        R.a10 = *(const float4*)(aR1 + kk * KC);
        R.a11 = *(const float4*)(aR1 + kk * KC + 4);
        int s = kk * 4 * 512 + bLane;
        R.bh0 = *(const bf16x8*)(bBase + s);
        R.bh1 = *(const bf16x8*)(bBase + s + 512);
        R.bl0 = *(const bf16x8*)(lBase + s);
        R.bl1 = *(const bf16x8*)(lBase + s + 512);
    };

    auto comp = [&](const Regs& R) {
        BF8 ah, al;
        split4(R.a00, &ah.u[0], &al.u[0]);
        split4(R.a01, &ah.u[2], &al.u[2]);
        acc[0][0] = __builtin_amdgcn_mfma_f32_16x16x32_bf16(ah.v, R.bh0, acc[0][0], 0, 0, 0);
        acc[0][0] = __builtin_amdgcn_mfma_f32_16x16x32_bf16(al.v, R.bh0, acc[0][0], 0, 0, 0);
        acc[0][0] = __builtin_amdgcn_mfma_f32_16x16x32_bf16(ah.v, R.bl0, acc[0][0], 0, 0, 0);
        acc[0][1] = __builtin_amdgcn_mfma_f32_16x16x32_bf16(ah.v, R.bh1, acc[0][1], 0, 0, 0);
        acc[0][1] = __builtin_amdgcn_mfma_f32_16x16x32_bf16(al.v, R.bh1, acc[0][1], 0, 0, 0);
        acc[0][1] = __builtin_amdgcn_mfma_f32_16x16x32_bf16(ah.v, R.bl1, acc[0][1], 0, 0, 0);
        split4(R.a10, &ah.u[0], &al.u[0]);
        split4(R.a11, &ah.u[2], &al.u[2]);
        acc[1][0] = __builtin_amdgcn_mfma_f32_16x16x32_bf16(ah.v, R.bh0, acc[1][0], 0, 0, 0);
        acc[1][0] = __builtin_amdgcn_mfma_f32_16x16x32_bf16(al.v, R.bh0, acc[1][0], 0, 0, 0);
        acc[1][0] = __builtin_amdgcn_mfma_f32_16x16x32_bf16(ah.v, R.bl0, acc[1][0], 0, 0, 0);
        acc[1][1] = __builtin_amdgcn_mfma_f32_16x16x32_bf16(ah.v, R.bh1, acc[1][1], 0, 0, 0);
        acc[1][1] = __builtin_amdgcn_mfma_f32_16x16x32_bf16(al.v, R.bh1, acc[1][1], 0, 0, 0);
        acc[1][1] = __builtin_amdgcn_mfma_f32_16x16x32_bf16(ah.v, R.bl1, acc[1][1], 0, 0, 0);
    };

    Regs RA, RB;
    loadc(0, RA);
#pragma unroll 2
    for (int kk = 0; kk < NCH; kk += 2) {
        loadc(kk + 1, RB);
        comp(RA);
        if (kk + 2 < NCH) loadc(kk + 2, RA);
        comp(RB);
    }

    // epilogue: C/D layout row=(lane>>4)*4+reg (token), col=lane&15 (expert)
#pragma unroll
    for (int mt = 0; mt < 2; ++mt)
#pragma unroll
        for (int n = 0; n < 2; ++n)
#pragma unroll
            for (int r = 0; r < 4; ++r)
                logits[(t0 + wm * 32 + mt * 16 + q * 4 + r) * NEXP
                       + wn * 32 + n * 16 + m] = acc[mt][n][r];
}

// Phase 2 standalone: 64 tokens/block, 8 waves (unchanged).
__global__ __launch_bounds__(512, 4) void moe_gate(
    const float* __restrict__ logits,
    float* __restrict__ out,
    float* __restrict__ ws)
{
    __shared__ float sLog[64 * 66];
    __shared__ float mxArr[64];
    __shared__ float smSum[NEXP];
    __shared__ int   hist[NEXP];

    const int tid = threadIdx.x;
    const int w   = tid >> 6;
    const int l   = tid & 63;
    const int t0  = blockIdx.x * 64;

    if (tid < NEXP) { smSum[tid] = 0.f; hist[tid] = 0; }

    const float4* src = (const float4*)(logits + (size_t)t0 * NEXP);
#pragma unroll
    for (int j = 0; j < 2; ++j) {
        int g = j * 512 + tid;          // float4 index 0..1023
        float4 v = src[g];
        int r = g >> 4, c = (g & 15) * 4;
        float* d = &sLog[r * 66 + c];
        d[0] = v.x; d[1] = v.y; d[2] = v.z; d[3] = v.w;
    }
    __syncthreads();

    // ---- phase 2a: softmax stats (lane = expert); wave w: tokens [8w, 8w+8)
    float regSm = 0.f;
    for (int j = 0; j < 8; ++j) {
        int t = w * 8 + j;
        float x = sLog[t * 66 + l];
        float mx = x;
#pragma unroll
        for (int off = 32; off; off >>= 1) mx = fmaxf(mx, __shfl_xor(mx, off));
        float p = __expf(x - mx);
        float sd = p;
#pragma unroll
        for (int off = 32; off; off >>= 1) sd += __shfl_xor(sd, off);
        regSm += p / sd;
        if (l == 0) mxArr[t] = mx;
    }
    atomicAdd(&smSum[l], regSm);
    __syncthreads();

    // ---- phase 2b: top-8 per token, lane = token (wave 0 only) ----
    if (w == 0) {
        const float mx = mxArr[l];
        unsigned long long s8[TK];
#pragma unroll
        for (int j = 0; j < TK; ++j) s8[j] = 0ull;
        for (int e = 0; e < NEXP; ++e) {
            float x = sLog[l * 66 + e];
            unsigned u = __float_as_uint(x);
            unsigned k32 = (u & 0x80000000u) ? ~u : (u | 0x80000000u);
            unsigned long long key = ((unsigned long long)k32 << 6)
                                   | (unsigned long long)(63 - e);
            if (key > s8[TK - 1]) {
#pragma unroll
                for (int j = 0; j < TK; ++j) {
                    unsigned long long hi = s8[j] > key ? s8[j] : key;
                    key = s8[j] > key ? key : s8[j];
                    s8[j] = hi;
                }
            }
        }
        float ev[TK]; int ei[TK]; float sum = 0.f;
#pragma unroll
        for (int j = 0; j < TK; ++j) {
            unsigned k32 = (unsigned)(s8[j] >> 6);
            unsigned u = (k32 >> 31) ? (k32 ^ 0x80000000u) : ~k32;
            ev[j] = __expf(__uint_as_float(u) - mx);
            sum += ev[j];
            ei[j] = 63 - (int)(s8[j] & 63ull);
        }
        int t = t0 + l;
        float4 i0 = make_float4((float)ei[0], (float)ei[1], (float)ei[2], (float)ei[3]);
        float4 i1 = make_float4((float)ei[4], (float)ei[5], (float)ei[6], (float)ei[7]);
        *(float4*)(out + (size_t)t * TK)     = i0;
        *(float4*)(out + (size_t)t * TK + 4) = i1;
        float rs = 1.f / (sum + 1e-20f);
        float4 w0 = make_float4(ev[0] * rs, ev[1] * rs, ev[2] * rs, ev[3] * rs);
        float4 w1 = make_float4(ev[4] * rs, ev[5] * rs, ev[6] * rs, ev[7] * rs);
        *(float4*)(out + (size_t)NTOK * TK + (size_t)t * TK)     = w0;
        *(float4*)(out + (size_t)NTOK * TK + (size_t)t * TK + 4) = w1;
#pragma unroll
        for (int j = 0; j < TK; ++j) atomicAdd(&hist[ei[j]], 1);
    }
    __syncthreads();

    if (tid < NEXP) {
        int b = blockIdx.x >> 6;            // 64 gate-blocks per batch element
        atomicAdd(&ws[b * NEXP + tid], (float)hist[tid]);
        atomicAdd(&ws[NB * NEXP + b * NEXP + tid], smSum[tid]);
    }
}

__global__ void moe_finalize(const float* __restrict__ ws, float* __restrict__ out)
{
    int e = threadIdx.x;   // 64 threads
    float cnt = 0.f, accv = 0.f;
#pragma unroll
    for (int b = 0; b < NB; ++b) {
        float c  = ws[b * NEXP + e];
        float sm = ws[NB * NEXP + b * NEXP + e];
        cnt += c;
        accv += c * sm;
    }
    out[(size_t)NTOK * TK * 2 + 1 + e] = cnt;   // expert_counts (as float)
#pragma unroll
    for (int off = 32; off; off >>= 1) accv += __shfl_xor(accv, off);
    if (e == 0) {
        float aux = 0.01f * accv * ((float)NEXP / ((float)SEQ * (float)TK))
                    / (float)SEQ / (float)NB;
        out[(size_t)NTOK * TK * 2] = aux;
    }
}

extern "C" void kernel_launch(void* const* d_in, const int* in_sizes, int n_in,
                              void* d_out, int out_size, void* d_ws, size_t ws_size,
                              hipStream_t stream)
{
    const float* hidden = (const float*)d_in[0];
    const float* weight = (const float*)d_in[1];
    float* out  = (float*)d_out;
    float* wsf  = (float*)d_ws;
    unsigned short* w2hi = (unsigned short*)(wsf + 2 * NB * NEXP);      // +4KB
    unsigned short* w2lo = w2hi + NEXP * HDIM;                          // +128KB
    float* logits = (float*)(w2lo + NEXP * HDIM);                       // +128KB, 8MB
    float* hCopy  = logits + (size_t)NTOK * NEXP;                       // +8MB, 134MB

    hipMemsetAsync(d_ws, 0, 2 * NB * NEXP * sizeof(float), stream);
    wsplit<<<32, 256, 0, stream>>>(weight, w2hi, w2lo);
    hcopy<<<2048, 256, 0, stream>>>((const float4*)hidden, (float4*)hCopy);
    moe_gemm<<<NBLK, NTHR, 0, stream>>>(hCopy, w2hi, w2lo, logits);
    moe_gate<<<NTOK / 64, 512, 0, stream>>>(logits, out, wsf);
    moe_finalize<<<1, 64, 0, stream>>>(wsf, out);
}

// Round 9
// 218.661 us; speedup vs baseline: 1.4041x; 1.4041x over previous
//
#include <hip/hip_runtime.h>

#define NTOK 32768      // 8*4096 tokens
#define HDIM 1024
#define NEXP 64
#define TK   8
#define NB   8
#define SEQ  4096

#define MB   64         // tokens per block
#define KC   64         // K chunk (16 chunks)
#define NCH  (HDIM / KC)
#define NTHR 512        // 8 waves: wm=w>>1 tokens [16wm,+16), wn=w&1 experts [32wn,+32)

// per-chunk buffer layout inside smem: A 16KB | Bhi 8KB | Blo 8KB
#define BUFSZ   32768
#define BHI_OFF 16384
#define BLO_OFF 24576

typedef __attribute__((ext_vector_type(8))) short bf16x8;   // 8 bf16 = 4 VGPRs
typedef __attribute__((ext_vector_type(4))) float f32x4;

union BF8 { bf16x8 v; unsigned u[4]; };

__device__ inline unsigned f2bf(float x) {          // RTN-even fp32 -> bf16 bits
    unsigned u = __float_as_uint(x);
    return (u + 0x7FFFu + ((u >> 16) & 1u)) >> 16;
}

__device__ inline void split4(float4 v, unsigned* hp, unsigned* lp) {
    unsigned h0 = f2bf(v.x), h1 = f2bf(v.y), h2 = f2bf(v.z), h3 = f2bf(v.w);
    unsigned l0 = f2bf(v.x - __uint_as_float(h0 << 16));
    unsigned l1 = f2bf(v.y - __uint_as_float(h1 << 16));
    unsigned l2 = f2bf(v.z - __uint_as_float(h2 << 16));
    unsigned l3 = f2bf(v.w - __uint_as_float(h3 << 16));
    hp[0] = h0 | (h1 << 16); hp[1] = h2 | (h3 << 16);
    lp[0] = l0 | (l1 << 16); lp[1] = l2 | (l3 << 16);
}

// async global->LDS, 16B/lane; LDS dest = wave-uniform base + lane*16
__device__ __forceinline__ void gl16(const void* g, void* l) {
    __builtin_amdgcn_global_load_lds(
        (const __attribute__((address_space(1))) void*)g,
        (__attribute__((address_space(3))) void*)l, 16, 0, 0);
}

// One-time: split W into Dekker hi/lo bf16 AND pre-arrange in MFMA B-fragment
// order: slot(c,s,n) holds 64 lanes x 16B; lane l -> B[e=n*16+(l&15)]
// [k=c*64+s*32+(l>>4)*8 .. +8]. Slot-major layout => chunk c's fragments are a
// CONTIGUOUS 8KB run (hi) + 8KB (lo): stageable with gl16.
__global__ void wsplit(const float* __restrict__ w,
                       unsigned short* __restrict__ whi,
                       unsigned short* __restrict__ wlo)
{
    int T = blockIdx.x * 256 + threadIdx.x;     // 8192 threads = 128 slots x 64
    int slot = T >> 6, l = T & 63;
    int c = slot >> 3, s = (slot >> 2) & 1, n = slot & 3;
    int e = n * 16 + (l & 15);
    int k = c * 64 + s * 32 + (l >> 4) * 8;
    const float* src = w + (size_t)e * HDIM + k;
    float4 v0 = *(const float4*)(src);
    float4 v1 = *(const float4*)(src + 4);
    unsigned hp[4], lp[4];
    split4(v0, &hp[0], &lp[0]);
    split4(v1, &hp[2], &lp[2]);
    ((uint4*)whi)[T] = make_uint4(hp[0], hp[1], hp[2], hp[3]);
    ((uint4*)wlo)[T] = make_uint4(lp[0], lp[1], lp[2], lp[3]);
}

// FINAL (== R5, best measured: 77us kernel / 216.7us bench).
// Roofline evidence (R8 ablation): a bare sequential float4 copy of the
// 134MB input takes 80us on this harness -- MORE than this fused kernel.
// Structural sweeps R0-R7 (occupancy 4x, traffic volume 2.5x, DRAM channel
// rotation, read/prefetch ordering, counted-vmcnt ring pipeline, and full
// removal of LDS+barriers) all landed 77-94us: the input-read stream is the
// invariant cost, and every other phase (GEMM, softmax stats, top-8, aux)
// rides under it. This kernel is at the harness's input-read roofline.
__global__ __launch_bounds__(NTHR, 4) void moe_main(
    const float* __restrict__ hidden,           // [NTOK][HDIM]
    const unsigned short* __restrict__ w2hi,    // frag-ordered bf16 hi
    const unsigned short* __restrict__ w2lo,    // frag-ordered bf16 lo
    float* __restrict__ out,                    // idx | w | aux | counts
    float* __restrict__ ws)                     // C[8][64] | Sm[8][64]
{
    __shared__ __align__(16) unsigned char smem[2 * BUFSZ];  // dbuf 2x(A|Bhi|Blo)
    float* sLog = (float*)smem;                              // [64][66] alias
    __shared__ float mxArr[MB];
    __shared__ float smSum[NEXP];
    __shared__ int   hist[NEXP];

    const int tid   = threadIdx.x;
    const int w     = tid >> 6;         // 0..7
    const int l     = tid & 63;
    const int m     = l & 15;
    const int q     = l >> 4;
    const int wm    = w >> 1;           // token group: rows [16*wm, 16*wm+16)
    const int wn    = w & 1;            // expert group: cols [32*wn, 32*wn+32)
    const int t0    = blockIdx.x * MB;
    const int wbase = tid & 448;        // wave-uniform slot base (tid & ~63)
    const int c0    = blockIdx.x & 15;  // chunk rotation start

    if (tid < NEXP) { smSum[tid] = 0.f; hist[tid] = 0; }

    f32x4 acc[2];
#pragma unroll
    for (int n = 0; n < 2; ++n) acc[n] = (f32x4)0.f;

    // prologue: stage chunk c0 (A XOR-swizzled + B linear) into buf 0
#pragma unroll
    for (int i = 0; i < 2; ++i) {
        int slot = i * NTHR + tid;
        int r = slot >> 4, p = slot & 15, b = p ^ (r & 15);
        gl16(hidden + (size_t)(t0 + r) * HDIM + c0 * KC + b * 4,
             smem + (size_t)(i * NTHR + wbase) * 16);
    }
    gl16(w2hi + (size_t)c0 * 4096 + (size_t)tid * 8, smem + BHI_OFF + (size_t)wbase * 16);
    gl16(w2lo + (size_t)c0 * 4096 + (size_t)tid * 8, smem + BLO_OFF + (size_t)wbase * 16);
    __syncthreads();

    for (int c = 0; c < NCH; ++c) {
        const unsigned char* Ab = smem + (c & 1) * BUFSZ;

        // (1) ALL LDS reads of chunk c first: B fragments into registers...
        bf16x8 bh[2][2], bl[2][2];
#pragma unroll
        for (int s = 0; s < 2; ++s)
#pragma unroll
            for (int n = 0; n < 2; ++n) {
                int off = ((s * 4 + wn * 2 + n) * 64 + l) * 16;
                bh[s][n] = *(const bf16x8*)(Ab + BHI_OFF + off);
                bl[s][n] = *(const bf16x8*)(Ab + BLO_OFF + off);
            }
        // ...and raw A float4s for both K32-steps
        float4 a0[2], a1[2];
#pragma unroll
        for (int s = 0; s < 2; ++s) {
            const int r  = wm * 16 + m;         // r & 15 == m
            const int b0 = s * 8 + q * 2;
            const int p0 = b0 ^ m, p1 = (b0 + 1) ^ m;
            a0[s] = *(const float4*)(Ab + ((size_t)r * 16 + p0) * 16);
            a1[s] = *(const float4*)(Ab + ((size_t)r * 16 + p1) * 16);
        }

        // (2) NOW issue the prefetch for chunk c+1 (other buffer). It stays in
        // flight through the whole compute phase; the vmcnt(0) drain sits at
        // the end-of-chunk barrier. No vmem/LDS reads below this point.
        if (c + 1 < NCH) {
            unsigned char* nb = smem + ((c + 1) & 1) * BUFSZ;
            const int cc1 = (c + 1 + c0) & 15;
            const int kc = cc1 * KC;
#pragma unroll
            for (int i = 0; i < 2; ++i) {
                int slot = i * NTHR + tid;
                int r = slot >> 4, p = slot & 15, b = p ^ (r & 15);
                gl16(hidden + (size_t)(t0 + r) * HDIM + kc + b * 4,
                     nb + (size_t)(i * NTHR + wbase) * 16);
            }
            gl16(w2hi + (size_t)cc1 * 4096 + (size_t)tid * 8,
                 nb + BHI_OFF + (size_t)wbase * 16);
            gl16(w2lo + (size_t)cc1 * 4096 + (size_t)tid * 8,
                 nb + BLO_OFF + (size_t)wbase * 16);
        }

        // (3) compute chunk c: 2 K32-steps, wave tile M=16 x N=32
#pragma unroll
        for (int s = 0; s < 2; ++s) {
            BF8 ah, al;
            split4(a0[s], &ah.u[0], &al.u[0]);
            split4(a1[s], &ah.u[2], &al.u[2]);
#pragma unroll
            for (int n = 0; n < 2; ++n) {
                acc[n] = __builtin_amdgcn_mfma_f32_16x16x32_bf16(ah.v, bh[s][n], acc[n], 0, 0, 0);
                acc[n] = __builtin_amdgcn_mfma_f32_16x16x32_bf16(al.v, bh[s][n], acc[n], 0, 0, 0);
                acc[n] = __builtin_amdgcn_mfma_f32_16x16x32_bf16(ah.v, bl[s][n], acc[n], 0, 0, 0);
            }
        }
        __syncthreads();    // (4) one barrier/chunk: prefetch drain overlapped
    }

    // epilogue: C/D layout row=(lane>>4)*4+reg (token), col=lane&15 (expert)
#pragma unroll
    for (int n = 0; n < 2; ++n)
#pragma unroll
        for (int r = 0; r < 4; ++r)
            sLog[(wm * 16 + q * 4 + r) * 66 + (wn * 2 + n) * 16 + m] = acc[n][r];
    __syncthreads();

    // ---- phase 2a: softmax stats (lane = expert); wave w: tokens [8w, 8w+8)
    float regSm = 0.f;
    for (int j = 0; j < 8; ++j) {
        int t = w * 8 + j;
        float x = sLog[t * 66 + l];
        float mx = x;
#pragma unroll
        for (int off = 32; off; off >>= 1) mx = fmaxf(mx, __shfl_xor(mx, off));
        float p = __expf(x - mx);
        float sd = p;
#pragma unroll
        for (int off = 32; off; off >>= 1) sd += __shfl_xor(sd, off);
        regSm += p / sd;
        if (l == 0) mxArr[t] = mx;
    }
    atomicAdd(&smSum[l], regSm);
    __syncthreads();

    // ---- phase 2b: top-8 per token, lane = token (wave 0 only) ----
    if (w == 0) {
        const float mx = mxArr[l];
        unsigned long long s8[TK];
#pragma unroll
        for (int j = 0; j < TK; ++j) s8[j] = 0ull;
        for (int e = 0; e < NEXP; ++e) {
            float x = sLog[l * 66 + e];
            unsigned u = __float_as_uint(x);
            unsigned k32 = (u & 0x80000000u) ? ~u : (u | 0x80000000u);
            unsigned long long key = ((unsigned long long)k32 << 6)
                                   | (unsigned long long)(63 - e);
            if (key > s8[TK - 1]) {
#pragma unroll
                for (int j = 0; j < TK; ++j) {
                    unsigned long long hi = s8[j] > key ? s8[j] : key;
                    key = s8[j] > key ? key : s8[j];
                    s8[j] = hi;
                }
            }
        }
        float ev[TK]; int ei[TK]; float sum = 0.f;
#pragma unroll
        for (int j = 0; j < TK; ++j) {
            unsigned k32 = (unsigned)(s8[j] >> 6);
            unsigned u = (k32 >> 31) ? (k32 ^ 0x80000000u) : ~k32;
            ev[j] = __expf(__uint_as_float(u) - mx);
            sum += ev[j];
            ei[j] = 63 - (int)(s8[j] & 63ull);
        }
        int t = t0 + l;
        float4 i0 = make_float4((float)ei[0], (float)ei[1], (float)ei[2], (float)ei[3]);
        float4 i1 = make_float4((float)ei[4], (float)ei[5], (float)ei[6], (float)ei[7]);
        *(float4*)(out + (size_t)t * TK)     = i0;
        *(float4*)(out + (size_t)t * TK + 4) = i1;
        float rs = 1.f / (sum + 1e-20f);
        float4 w0 = make_float4(ev[0] * rs, ev[1] * rs, ev[2] * rs, ev[3] * rs);
        float4 w1 = make_float4(ev[4] * rs, ev[5] * rs, ev[6] * rs, ev[7] * rs);
        *(float4*)(out + (size_t)NTOK * TK + (size_t)t * TK)     = w0;
        *(float4*)(out + (size_t)NTOK * TK + (size_t)t * TK + 4) = w1;
#pragma unroll
        for (int j = 0; j < TK; ++j) atomicAdd(&hist[ei[j]], 1);
    }
    __syncthreads();

    if (tid < NEXP) {
        int b = blockIdx.x >> 6;            // 64 blocks per batch element
        atomicAdd(&ws[b * NEXP + tid], (float)hist[tid]);
        atomicAdd(&ws[NB * NEXP + b * NEXP + tid], smSum[tid]);
    }
}

__global__ void moe_finalize(const float* __restrict__ ws, float* __restrict__ out)
{
    int e = threadIdx.x;   // 64 threads
    float cnt = 0.f, accv = 0.f;
#pragma unroll
    for (int b = 0; b < NB; ++b) {
        float c  = ws[b * NEXP + e];
        float sm = ws[NB * NEXP + b * NEXP + e];
        cnt += c;
        accv += c * sm;
    }
    out[(size_t)NTOK * TK * 2 + 1 + e] = cnt;   // expert_counts (as float)
#pragma unroll
    for (int off = 32; off; off >>= 1) accv += __shfl_xor(accv, off);
    if (e == 0) {
        float aux = 0.01f * accv * ((float)NEXP / ((float)SEQ * (float)TK))
                    / (float)SEQ / (float)NB;
        out[(size_t)NTOK * TK * 2] = aux;
    }
}

extern "C" void kernel_launch(void* const* d_in, const int* in_sizes, int n_in,
                              void* d_out, int out_size, void* d_ws, size_t ws_size,
                              hipStream_t stream)
{
    const float* hidden = (const float*)d_in[0];
    const float* weight = (const float*)d_in[1];
    float* out  = (float*)d_out;
    float* wsf  = (float*)d_ws;
    unsigned short* w2hi = (unsigned short*)(wsf + 2 * NB * NEXP);  // +4096 B
    unsigned short* w2lo = w2hi + NEXP * HDIM;

    hipMemsetAsync(d_ws, 0, 2 * NB * NEXP * sizeof(float), stream);
    wsplit<<<32, 256, 0, stream>>>(weight, w2hi, w2lo);
    moe_main<<<NTOK / MB, NTHR, 0, stream>>>(hidden, w2hi, w2lo, out, wsf);
    moe_finalize<<<1, 64, 0, stream>>>(wsf, out);
}